// Round 4
// baseline (513.568 us; speedup 1.0000x reference)
//
#include <hip/hip_runtime.h>
#include <hip/hip_bf16.h>
#include <math.h>

constexpr int NB   = 4;
constexpr int LL   = 8192;
constexpr int DD   = 256;
constexpr int NH   = 8;
constexpr int HDIM = 32;
constexpr int WNN  = 9;
constexpr int PPAD = 4;

constexpr int CW  = 32;         // windows per attention block
constexpr int RSN = CW + 8;     // 40 staged rows
constexpr int SST = 260;        // bf16 LDS row stride (65 8B-slots, odd -> row spreads banks)
constexpr int PST = 256;        // pos rows: compact stride (reads are broadcast -> conflict-immune)

typedef __attribute__((ext_vector_type(8))) short bf16x8;
typedef __attribute__((ext_vector_type(4))) float f32x4;

__device__ inline short f2bf(float f) {
  __hip_bfloat16 h = __float2bfloat16(f);
  short s; __builtin_memcpy(&s, &h, 2); return s;
}
__device__ inline float bf2f(short s) {
  unsigned u = ((unsigned)(unsigned short)s) << 16;
  float f; __builtin_memcpy(&f, &u, 4); return f;
}

// ---------------- x -> bf16 ----------------
__global__ __launch_bounds__(256) void conv_x(const float* __restrict__ x, short* __restrict__ XB) {
  size_t i = ((size_t)blockIdx.x * 256 + threadIdx.x) * 4;
  float4 v = *(const float4*)(x + i);
  short4 o; o.x = f2bf(v.x); o.y = f2bf(v.y); o.z = f2bf(v.z); o.w = f2bf(v.w);
  *(short4*)(XB + i) = o;
}

// ---------------- weights: Wq/Wk/Wv/Wo transposed->bf16 (n-major), Wout->bf16 straight ----------------
__global__ __launch_bounds__(256) void prep_w(
    const float* __restrict__ Wq, const float* __restrict__ Wk, const float* __restrict__ Wv,
    const float* __restrict__ Wo, const float* __restrict__ Wout,
    short* __restrict__ WqT, short* __restrict__ WkT, short* __restrict__ WvT,
    short* __restrict__ WoT, short* __restrict__ WoutB) {
  const int t = threadIdx.x, b = blockIdx.x;
  if (b < 4) {
    const float* W = (b == 0) ? Wq : (b == 1) ? Wk : (b == 2) ? Wv : Wo;
    short* T = (b == 0) ? WqT : (b == 1) ? WkT : (b == 2) ? WvT : WoT;
    for (int k = 0; k < 256; k += 4) {
      short4 o;
      o.x = f2bf(W[(size_t)(k + 0) * 256 + t]);
      o.y = f2bf(W[(size_t)(k + 1) * 256 + t]);
      o.z = f2bf(W[(size_t)(k + 2) * 256 + t]);
      o.w = f2bf(W[(size_t)(k + 3) * 256 + t]);
      *(short4*)&T[(size_t)t * 256 + k] = o;
    }
  } else {
    for (int i = t; i < 16384; i += 256) {
      float4 v = *(const float4*)(Wout + (size_t)i * 4);
      short4 o; o.x = f2bf(v.x); o.y = f2bf(v.y); o.z = f2bf(v.z); o.w = f2bf(v.w);
      *(short4*)(WoutB + (size_t)i * 4) = o;
    }
  }
}

// ---------------- pos projection (fp32 math, bf16 out) ----------------
__global__ __launch_bounds__(256) void pos_proj(
    const float* __restrict__ pos,
    const float* __restrict__ Wq, const float* __restrict__ Wk, const float* __restrict__ Wv,
    short* __restrict__ PQb, short* __restrict__ PKb, short* __restrict__ PVb) {
  __shared__ float ps[256];
  const int t = threadIdx.x, wrow = blockIdx.x, wh = blockIdx.y;
  const float* W = (wh == 0) ? Wq : (wh == 1) ? Wk : Wv;
  short* P = (wh == 0) ? PQb : (wh == 1) ? PKb : PVb;
  ps[t] = pos[wrow * 256 + t];
  __syncthreads();
  float a = 0.f;
  for (int d = 0; d < 256; ++d) a += ps[d] * W[(size_t)d * 256 + t];
  P[wrow * 256 + t] = f2bf(a);
}

// ---------------- QKV projection via MFMA with register-dbuf prefetch ----------------
__global__ __launch_bounds__(256) void qkv_mfma(
    const short* __restrict__ XB,
    const short* __restrict__ WT0, const short* __restrict__ WT1, const short* __restrict__ WT2,
    short* __restrict__ O0, short* __restrict__ O1, short* __restrict__ O2) {
  const int t = threadIdx.x, w = t >> 6, lane = t & 63, q = lane >> 4, m = lane & 15;
  const size_t row0 = (size_t)blockIdx.x * 64;
  const short* WT = (blockIdx.y == 0) ? WT0 : (blockIdx.y == 1) ? WT1 : WT2;
  short* O = (blockIdx.y == 0) ? O0 : (blockIdx.y == 1) ? O1 : O2;

  f32x4 acc[4][4];
#pragma unroll
  for (int i = 0; i < 4; ++i)
#pragma unroll
    for (int j = 0; j < 4; ++j) acc[i][j] = (f32x4){0.f, 0.f, 0.f, 0.f};

  const short* abase = XB + (row0 + m) * (size_t)256 + q * 8;
  const short* bbase = WT + (size_t)(w * 64 + m) * 256 + q * 8;
  bf16x8 a[4], b[4];
#pragma unroll
  for (int i = 0; i < 4; ++i) a[i] = *(const bf16x8*)(abase + (size_t)i * 4096);
#pragma unroll
  for (int j = 0; j < 4; ++j) b[j] = *(const bf16x8*)(bbase + (size_t)j * 4096);
#pragma unroll
  for (int kk = 0; kk < 8; ++kk) {
    bf16x8 an[4], bn[4];
    if (kk < 7) {
#pragma unroll
      for (int i = 0; i < 4; ++i) an[i] = *(const bf16x8*)(abase + (size_t)i * 4096 + (kk + 1) * 32);
#pragma unroll
      for (int j = 0; j < 4; ++j) bn[j] = *(const bf16x8*)(bbase + (size_t)j * 4096 + (kk + 1) * 32);
    }
#pragma unroll
    for (int i = 0; i < 4; ++i)
#pragma unroll
      for (int j = 0; j < 4; ++j)
        acc[i][j] = __builtin_amdgcn_mfma_f32_16x16x32_bf16(a[i], b[j], acc[i][j], 0, 0, 0);
    if (kk < 7) {
#pragma unroll
      for (int i = 0; i < 4; ++i) a[i] = an[i];
#pragma unroll
      for (int j = 0; j < 4; ++j) b[j] = bn[j];
    }
  }
#pragma unroll
  for (int i = 0; i < 4; ++i)
#pragma unroll
    for (int j = 0; j < 4; ++j)
#pragma unroll
      for (int r = 0; r < 4; ++r) {
        size_t row = row0 + i * 16 + q * 4 + r;
        int col = w * 64 + j * 16 + m;
        O[row * 256 + col] = f2bf(acc[i][j][r]);
      }
}

// ---------------- windowed attention v6 ----------------
// v5 -> v6: keep the 50.8 KB LDS overlay (sA holds Q in phase 1, V in phase 2)
// but drop the register prefetch of V. Holding vreg[10]+pvreg[3] (26 VGPR)
// live across the unrolled score region (peak ~ sc[81]+qv/kv[72]) drove the
// allocator into scratch-spill mode in BOTH v4 (bound 3: VGPR 84) and v5
// (bound 2: VGPR 128): ~850 MB/dispatch of spill traffic, 277-470 us.
// Instead V+posV are loaded from global AT THE PHASE FLIP (short4 load ->
// immediate ds_write, registers die instantly). Latency of the flip loads is
// hidden by the other 2 co-resident blocks (the point of 3 blocks/CU).
// HBM traffic identical to v2/R1 (~47 MB real).
// NOTE: SQ_LDS_BANK_CONFLICT = 3538944 is IDENTICAL across all swizzles ->
// structural ds_read_b64 floor (512 B/wave vs 128 B/cy LDS). Closed axis.
__global__ __launch_bounds__(256, 2) void attn_kernel(
    const short* __restrict__ XQb, const short* __restrict__ XKb, const short* __restrict__ XVb,
    const short* __restrict__ PQb, const short* __restrict__ PKb, const short* __restrict__ PVb,
    short* __restrict__ CTXB) {
  __shared__ short sA[RSN * SST];   // phase1: Q   phase2: V
  __shared__ short sK[RSN * SST];   // K
  __shared__ short pA[WNN * PST];   // phase1: posQ  phase2: posV
  __shared__ short pK[WNN * PST];   // posK

  const int t = threadIdx.x;
  const int nblk = LL / CW;
  const int b = blockIdx.x / nblk;
  const int n0 = (blockIdx.x % nblk) * CW;
  const size_t base = (size_t)b * LL * DD;

  // staging lane->column mapping: lane lq writes physical slot lq of its row.
  // inverse of p(h,c): h = (lq&31)>>2, c = (lq&3) | ((lq>>5)<<2); logical
  // short4 index = h*8 + c.
  const int lq   = t & 63;
  const int sh_h = (lq & 31) >> 2;
  const int sh_c = (lq & 3) | ((lq >> 5) << 2);
  const int gcol = (sh_h * 8 + sh_c) * 4;   // logical short offset of this lane's short4
  const int pcol = lq * 4;                  // physical short offset (slot lq)

  // ---- stage Q,K halo rows ----
#pragma unroll
  for (int i = 0; i < RSN / 4; ++i) {   // 10 iters, one full row per wave
    int r = (t >> 6) + i * 4;
    int j = n0 - PPAD + r;
    short4 vq = {0, 0, 0, 0}, vk = vq;
    if (j >= 0 && j < LL) {
      size_t off = base + (size_t)j * DD + gcol;
      vq = *(const short4*)(XQb + off);
      vk = *(const short4*)(XKb + off);
    }
    *(short4*)&sA[r * SST + pcol] = vq;
    *(short4*)&sK[r * SST + pcol] = vk;
  }
#pragma unroll
  for (int i = 0; i < 3; ++i) {
    int r = (t >> 6) + i * 4;
    if (r < WNN) {
      *(short4*)&pA[r * PST + pcol] = *(const short4*)(PQb + r * DD + gcol);
      *(short4*)&pK[r * PST + pcol] = *(const short4*)(PKb + r * DD + gcol);
    }
  }
  __syncthreads();

  const int n = t >> 3;        // window within block
  const int h = t & 7;         // head
  const int hoff = h * HDIM;   // logical head offset (global writes only)

  float sc[WNN][WNN];
#pragma unroll
  for (int qi = 0; qi < WNN; ++qi)
#pragma unroll
    for (int ki = 0; ki < WNN; ++ki) sc[qi][ki] = 0.f;

  // scores: chunked K-dim so each q/k element is converted once, used 9x
#pragma unroll
  for (int c = 0; c < 8; ++c) {
    const int cph = h * 16 + (c & 3) * 4 + (c >> 2) * 128;  // physical short offset
    float qv[WNN][4], kv[WNN][4];
#pragma unroll
    for (int r = 0; r < WNN; ++r) {
      short4 xa = *(const short4*)&sA[(n + r) * SST + cph];
      short4 pa = *(const short4*)&pA[r * PST + cph];
      qv[r][0] = bf2f(xa.x) + bf2f(pa.x);
      qv[r][1] = bf2f(xa.y) + bf2f(pa.y);
      qv[r][2] = bf2f(xa.z) + bf2f(pa.z);
      qv[r][3] = bf2f(xa.w) + bf2f(pa.w);
      short4 xb = *(const short4*)&sK[(n + r) * SST + cph];
      short4 pb = *(const short4*)&pK[r * PST + cph];
      kv[r][0] = bf2f(xb.x) + bf2f(pb.x);
      kv[r][1] = bf2f(xb.y) + bf2f(pb.y);
      kv[r][2] = bf2f(xb.z) + bf2f(pb.z);
      kv[r][3] = bf2f(xb.w) + bf2f(pb.w);
    }
#pragma unroll
    for (int qi = 0; qi < WNN; ++qi)
#pragma unroll
      for (int ki = 0; ki < WNN; ++ki)
        sc[qi][ki] += qv[qi][0] * kv[ki][0] + qv[qi][1] * kv[ki][1] +
                      qv[qi][2] * kv[ki][2] + qv[qi][3] * kv[ki][3];
  }

  // softmax per q-row, accumulate column sums (all thread-local)
  float cs[WNN];
#pragma unroll
  for (int ki = 0; ki < WNN; ++ki) cs[ki] = 0.f;
  const float scale = 0.17677669529663687f;  // 1/sqrt(32)
#pragma unroll
  for (int qi = 0; qi < WNN; ++qi) {
    float mx = sc[qi][0];
#pragma unroll
    for (int ki = 1; ki < WNN; ++ki) mx = fmaxf(mx, sc[qi][ki]);
    float e[WNN], sum = 0.f;
#pragma unroll
    for (int ki = 0; ki < WNN; ++ki) { e[ki] = __expf((sc[qi][ki] - mx) * scale); sum += e[ki]; }
    float inv = 1.f / sum;
#pragma unroll
    for (int ki = 0; ki < WNN; ++ki) cs[ki] += e[ki] * inv;
  }

  // ---- phase flip: load V fresh from global, write into Q's buffer ----
  __syncthreads();                      // all phase-1 reads of sA/pA done
#pragma unroll
  for (int i = 0; i < RSN / 4; ++i) {
    int r = (t >> 6) + i * 4;
    int j = n0 - PPAD + r;
    short4 vv = {0, 0, 0, 0};
    if (j >= 0 && j < LL) vv = *(const short4*)(XVb + base + (size_t)j * DD + gcol);
    *(short4*)&sA[r * SST + pcol] = vv;
  }
#pragma unroll
  for (int i = 0; i < 3; ++i) {
    int r = (t >> 6) + i * 4;
    if (r < WNN) *(short4*)&pA[r * PST + pcol] = *(const short4*)(PVb + r * DD + gcol);
  }
  __syncthreads();

  // ctx: weighted sum of v rows (+ pos-v), write bf16 (global layout unchanged)
#pragma unroll
  for (int c = 0; c < 8; ++c) {
    const int cph = h * 16 + (c & 3) * 4 + (c >> 2) * 128;
    float o0 = 0.f, o1 = 0.f, o2 = 0.f, o3 = 0.f;
#pragma unroll
    for (int ki = 0; ki < WNN; ++ki) {
      short4 xv4 = *(const short4*)&sA[(n + ki) * SST + cph];
      short4 pv4 = *(const short4*)&pA[ki * PST + cph];
      float wt = cs[ki];
      o0 += wt * (bf2f(xv4.x) + bf2f(pv4.x));
      o1 += wt * (bf2f(xv4.y) + bf2f(pv4.y));
      o2 += wt * (bf2f(xv4.z) + bf2f(pv4.z));
      o3 += wt * (bf2f(xv4.w) + bf2f(pv4.w));
    }
    short4 os; os.x = f2bf(o0); os.y = f2bf(o1); os.z = f2bf(o2); os.w = f2bf(o3);
    *(short4*)(CTXB + base + (size_t)(n0 + n) * DD + hoff + c * 4) = os;
  }
}

// CAUTION: softmax scale note — reference scales scores BEFORE softmax; we fold
// the scale into the exp argument ((sc-mx)*scale) which is equivalent since mx
// is the max of unscaled scores and scale>0.

// ---------------- fused out stage via MFMA ----------------
__global__ __launch_bounds__(256) void out_mfma(
    const short* __restrict__ CTXB, const float* __restrict__ X,
    const short* __restrict__ WoT, const short* __restrict__ WoutB,
    const float* __restrict__ bo,
    const float* __restrict__ g1, const float* __restrict__ b1,
    const float* __restrict__ g2, const float* __restrict__ b2,
    float* __restrict__ out) {
  __shared__ short ar[64 * 264];
  __shared__ float ws1[64][4], ws2[64][4];
  __shared__ float msh[64], rsh[64];
  __shared__ float g1s[256], b1s[256], g2s[256], b2s[256], bos[256];
  const int t = threadIdx.x, w = t >> 6, lane = t & 63, q = lane >> 4, m = lane & 15;
  const size_t row0 = (size_t)blockIdx.x * 64;
  g1s[t] = g1[t]; b1s[t] = b1[t]; g2s[t] = g2[t]; b2s[t] = b2[t]; bos[t] = bo[t];

  f32x4 acc[4][4];
#pragma unroll
  for (int i = 0; i < 4; ++i)
#pragma unroll
    for (int j = 0; j < 4; ++j) acc[i][j] = (f32x4){0.f, 0.f, 0.f, 0.f};

  // GEMM1: ctx @ Wo (register-dbuf prefetch)
  const short* abase = CTXB + (row0 + m) * (size_t)256 + q * 8;
  const short* bbase = WoT + (size_t)(w * 64 + m) * 256 + q * 8;
  {
    bf16x8 a[4], b[4];
#pragma unroll
    for (int i = 0; i < 4; ++i) a[i] = *(const bf16x8*)(abase + (size_t)i * 4096);
#pragma unroll
    for (int j = 0; j < 4; ++j) b[j] = *(const bf16x8*)(bbase + (size_t)j * 4096);
#pragma unroll
    for (int kk = 0; kk < 8; ++kk) {
      bf16x8 an[4], bn[4];
      if (kk < 7) {
#pragma unroll
        for (int i = 0; i < 4; ++i) an[i] = *(const bf16x8*)(abase + (size_t)i * 4096 + (kk + 1) * 32);
#pragma unroll
        for (int j = 0; j < 4; ++j) bn[j] = *(const bf16x8*)(bbase + (size_t)j * 4096 + (kk + 1) * 32);
      }
#pragma unroll
      for (int i = 0; i < 4; ++i)
#pragma unroll
        for (int j = 0; j < 4; ++j)
          acc[i][j] = __builtin_amdgcn_mfma_f32_16x16x32_bf16(a[i], b[j], acc[i][j], 0, 0, 0);
      if (kk < 7) {
#pragma unroll
        for (int i = 0; i < 4; ++i) a[i] = an[i];
#pragma unroll
        for (int j = 0; j < 4; ++j) b[j] = bn[j];
      }
    }
  }

  // + skip, LN1 partial stats
  float s1v[4][4], s2v[4][4];
#pragma unroll
  for (int i = 0; i < 4; ++i)
#pragma unroll
    for (int r = 0; r < 4; ++r) {
      float a0 = 0.f, b0 = 0.f;
#pragma unroll
      for (int j = 0; j < 4; ++j) {
        float v = acc[i][j][r] + X[(row0 + i * 16 + q * 4 + r) * 256 + w * 64 + j * 16 + m];
        acc[i][j][r] = v; a0 += v; b0 += v * v;
      }
      s1v[i][r] = a0; s2v[i][r] = b0;
    }
#pragma unroll
  for (int i = 0; i < 4; ++i)
#pragma unroll
    for (int r = 0; r < 4; ++r)
#pragma unroll
      for (int msk = 1; msk < 16; msk <<= 1) {
        s1v[i][r] += __shfl_xor(s1v[i][r], msk, 64);
        s2v[i][r] += __shfl_xor(s2v[i][r], msk, 64);
      }
  if (m == 0) {
#pragma unroll
    for (int i = 0; i < 4; ++i)
#pragma unroll
      for (int r = 0; r < 4; ++r) {
        ws1[i * 16 + q * 4 + r][w] = s1v[i][r];
        ws2[i * 16 + q * 4 + r][w] = s2v[i][r];
      }
  }
  __syncthreads();
  if (t < 64) {
    float a0 = 0.f, b0 = 0.f;
#pragma unroll
    for (int ww = 0; ww < 4; ++ww) { a0 += ws1[t][ww]; b0 += ws2[t][ww]; }
    float mean = a0 * (1.f / 256.f);
    float var = b0 * (1.f / 256.f) - mean * mean;
    msh[t] = mean; rsh[t] = rsqrtf(var + 1e-5f);
  }
  __syncthreads();

#pragma unroll
  for (int i = 0; i < 4; ++i)
#pragma unroll
    for (int r = 0; r < 4; ++r) {
      int row = i * 16 + q * 4 + r;
      float mean = msh[row], rst = rsh[row];
#pragma unroll
      for (int j = 0; j < 4; ++j) {
        int col = w * 64 + j * 16 + m;
        float v = (acc[i][j][r] - mean) * rst * g1s[col] + b1s[col];
        ar[row * 264 + col] = f2bf(v);
      }
    }
  __syncthreads();

  // GEMM2: ar @ Wout^T (A from LDS, B global with prefetch)
#pragma unroll
  for (int i = 0; i < 4; ++i)
#pragma unroll
    for (int j = 0; j < 4; ++j) acc[i][j] = (f32x4){0.f, 0.f, 0.f, 0.f};
  const short* b2base = WoutB + (size_t)(w * 64 + m) * 256 + q * 8;
  {
    bf16x8 b[4];
#pragma unroll
    for (int j = 0; j < 4; ++j) b[j] = *(const bf16x8*)(b2base + (size_t)j * 4096);
#pragma unroll
    for (int kk = 0; kk < 8; ++kk) {
      bf16x8 bn[4];
      if (kk < 7) {
#pragma unroll
        for (int j = 0; j < 4; ++j) bn[j] = *(const bf16x8*)(b2base + (size_t)j * 4096 + (kk + 1) * 32);
      }
      bf16x8 a[4];
#pragma unroll
      for (int i = 0; i < 4; ++i) a[i] = *(const bf16x8*)&ar[(i * 16 + m) * 264 + kk * 32 + q * 8];
#pragma unroll
      for (int i = 0; i < 4; ++i)
#pragma unroll
        for (int j = 0; j < 4; ++j)
          acc[i][j] = __builtin_amdgcn_mfma_f32_16x16x32_bf16(a[i], b[j], acc[i][j], 0, 0, 0);
      if (kk < 7) {
#pragma unroll
        for (int j = 0; j < 4; ++j) b[j] = bn[j];
      }
    }
  }

  // + bias + residual, LN2 stats
#pragma unroll
  for (int i = 0; i < 4; ++i)
#pragma unroll
    for (int r = 0; r < 4; ++r) {
      int row = i * 16 + q * 4 + r;
      float a0 = 0.f, b0 = 0.f;
#pragma unroll
      for (int j = 0; j < 4; ++j) {
        int col = w * 64 + j * 16 + m;
        float v = acc[i][j][r] + bos[col] + bf2f(ar[row * 264 + col]);
        acc[i][j][r] = v; a0 += v; b0 += v * v;
      }
      s1v[i][r] = a0; s2v[i][r] = b0;
    }
#pragma unroll
  for (int i = 0; i < 4; ++i)
#pragma unroll
    for (int r = 0; r < 4; ++r)
#pragma unroll
      for (int msk = 1; msk < 16; msk <<= 1) {
        s1v[i][r] += __shfl_xor(s1v[i][r], msk, 64);
        s2v[i][r] += __shfl_xor(s2v[i][r], msk, 64);
      }
  if (m == 0) {
#pragma unroll
    for (int i = 0; i < 4; ++i)
#pragma unroll
      for (int r = 0; r < 4; ++r) {
        ws1[i * 16 + q * 4 + r][w] = s1v[i][r];
        ws2[i * 16 + q * 4 + r][w] = s2v[i][r];
      }
  }
  __syncthreads();
  if (t < 64) {
    float a0 = 0.f, b0 = 0.f;
#pragma unroll
    for (int ww = 0; ww < 4; ++ww) { a0 += ws1[t][ww]; b0 += ws2[t][ww]; }
    float mean = a0 * (1.f / 256.f);
    float var = b0 * (1.f / 256.f) - mean * mean;
    msh[t] = mean; rsh[t] = rsqrtf(var + 1e-5f);
  }
  __syncthreads();

#pragma unroll
  for (int i = 0; i < 4; ++i)
#pragma unroll
    for (int r = 0; r < 4; ++r) {
      int row = i * 16 + q * 4 + r;
      float mean = msh[row], rst = rsh[row];
#pragma unroll
      for (int j = 0; j < 4; ++j) {
        int col = w * 64 + j * 16 + m;
        float v = (acc[i][j][r] - mean) * rst * g2s[col] + b2s[col];
        out[(row0 + row) * 256 + col] = fmaxf(v, 0.f);
      }
    }
}

extern "C" void kernel_launch(void* const* d_in, const int* in_sizes, int n_in,
                              void* d_out, int out_size, void* d_ws, size_t ws_size,
                              hipStream_t stream) {
  const float* x    = (const float*)d_in[0];
  const float* Wq   = (const float*)d_in[1];
  const float* Wk   = (const float*)d_in[2];
  const float* Wv   = (const float*)d_in[3];
  const float* Wo   = (const float*)d_in[4];
  const float* pos  = (const float*)d_in[5];
  const float* Wout = (const float*)d_in[6];
  const float* bo   = (const float*)d_in[7];
  const float* g1   = (const float*)d_in[8];
  const float* b1   = (const float*)d_in[9];
  const float* g2   = (const float*)d_in[10];
  const float* b2   = (const float*)d_in[11];
  float* out = (float*)d_out;

  const size_t nel = (size_t)NB * LL * DD;
  char* wsb = (char*)d_ws;
  short* XB   = (short*)wsb; wsb += nel * 2;
  short* XQb  = (short*)wsb; wsb += nel * 2;
  short* XKb  = (short*)wsb; wsb += nel * 2;
  short* XVb  = (short*)wsb; wsb += nel * 2;
  short* CTXB = (short*)wsb; wsb += nel * 2;
  short* WqT   = (short*)wsb; wsb += 65536 * 2;
  short* WkT   = (short*)wsb; wsb += 65536 * 2;
  short* WvT   = (short*)wsb; wsb += 65536 * 2;
  short* WoT   = (short*)wsb; wsb += 65536 * 2;
  short* WoutB = (short*)wsb; wsb += 65536 * 2;
  short* PQb = (short*)wsb; wsb += WNN * DD * 2;
  short* PKb = (short*)wsb; wsb += WNN * DD * 2;
  short* PVb = (short*)wsb; wsb += WNN * DD * 2;

  conv_x<<<(unsigned)(nel / 4 / 256), 256, 0, stream>>>(x, XB);
  prep_w<<<5, 256, 0, stream>>>(Wq, Wk, Wv, Wo, Wout, WqT, WkT, WvT, WoT, WoutB);
  pos_proj<<<dim3(WNN, 3), 256, 0, stream>>>(pos, Wq, Wk, Wv, PQb, PKb, PVb);
  qkv_mfma<<<dim3((unsigned)(NB * LL / 64), 3), 256, 0, stream>>>(XB, WqT, WkT, WvT, XQb, XKb, XVb);
  attn_kernel<<<NB * (LL / CW), 256, 0, stream>>>(XQb, XKb, XVb, PQb, PKb, PVb, CTXB);
  out_mfma<<<(unsigned)(NB * LL / 64), 256, 0, stream>>>(CTXB, x, WoT, WoutB, bo, g1, b1, g2, b2, out);
}

// Round 5
// 508.164 us; speedup vs baseline: 1.0106x; 1.0106x over previous
//
#include <hip/hip_runtime.h>
#include <hip/hip_bf16.h>
#include <math.h>

constexpr int NB   = 4;
constexpr int LL   = 8192;
constexpr int DD   = 256;
constexpr int NH   = 8;
constexpr int HDIM = 32;
constexpr int WNN  = 9;
constexpr int PPAD = 4;

constexpr int CW  = 32;         // windows per attention block
constexpr int RSN = CW + 8;     // 40 staged rows
constexpr int SST = 260;        // bf16 LDS row stride (65 8B-slots, odd -> row spreads banks)
constexpr int PST = 256;        // pos rows: compact stride (reads are broadcast -> conflict-immune)

typedef __attribute__((ext_vector_type(8))) short bf16x8;
typedef __attribute__((ext_vector_type(4))) float f32x4;

__device__ inline short f2bf(float f) {
  __hip_bfloat16 h = __float2bfloat16(f);
  short s; __builtin_memcpy(&s, &h, 2); return s;
}
__device__ inline float bf2f(short s) {
  unsigned u = ((unsigned)(unsigned short)s) << 16;
  float f; __builtin_memcpy(&f, &u, 4); return f;
}

// ---------------- x -> bf16 ----------------
__global__ __launch_bounds__(256) void conv_x(const float* __restrict__ x, short* __restrict__ XB) {
  size_t i = ((size_t)blockIdx.x * 256 + threadIdx.x) * 4;
  float4 v = *(const float4*)(x + i);
  short4 o; o.x = f2bf(v.x); o.y = f2bf(v.y); o.z = f2bf(v.z); o.w = f2bf(v.w);
  *(short4*)(XB + i) = o;
}

// ---------------- weights: Wq/Wk/Wv/Wo transposed->bf16 (n-major), Wout->bf16 straight ----------------
__global__ __launch_bounds__(256) void prep_w(
    const float* __restrict__ Wq, const float* __restrict__ Wk, const float* __restrict__ Wv,
    const float* __restrict__ Wo, const float* __restrict__ Wout,
    short* __restrict__ WqT, short* __restrict__ WkT, short* __restrict__ WvT,
    short* __restrict__ WoT, short* __restrict__ WoutB) {
  const int t = threadIdx.x, b = blockIdx.x;
  if (b < 4) {
    const float* W = (b == 0) ? Wq : (b == 1) ? Wk : (b == 2) ? Wv : Wo;
    short* T = (b == 0) ? WqT : (b == 1) ? WkT : (b == 2) ? WvT : WoT;
    for (int k = 0; k < 256; k += 4) {
      short4 o;
      o.x = f2bf(W[(size_t)(k + 0) * 256 + t]);
      o.y = f2bf(W[(size_t)(k + 1) * 256 + t]);
      o.z = f2bf(W[(size_t)(k + 2) * 256 + t]);
      o.w = f2bf(W[(size_t)(k + 3) * 256 + t]);
      *(short4*)&T[(size_t)t * 256 + k] = o;
    }
  } else {
    for (int i = t; i < 16384; i += 256) {
      float4 v = *(const float4*)(Wout + (size_t)i * 4);
      short4 o; o.x = f2bf(v.x); o.y = f2bf(v.y); o.z = f2bf(v.z); o.w = f2bf(v.w);
      *(short4*)(WoutB + (size_t)i * 4) = o;
    }
  }
}

// ---------------- pos projection (fp32 math, bf16 out) ----------------
__global__ __launch_bounds__(256) void pos_proj(
    const float* __restrict__ pos,
    const float* __restrict__ Wq, const float* __restrict__ Wk, const float* __restrict__ Wv,
    short* __restrict__ PQb, short* __restrict__ PKb, short* __restrict__ PVb) {
  __shared__ float ps[256];
  const int t = threadIdx.x, wrow = blockIdx.x, wh = blockIdx.y;
  const float* W = (wh == 0) ? Wq : (wh == 1) ? Wk : Wv;
  short* P = (wh == 0) ? PQb : (wh == 1) ? PKb : PVb;
  ps[t] = pos[wrow * 256 + t];
  __syncthreads();
  float a = 0.f;
  for (int d = 0; d < 256; ++d) a += ps[d] * W[(size_t)d * 256 + t];
  P[wrow * 256 + t] = f2bf(a);
}

// ---------------- QKV projection via MFMA with register-dbuf prefetch ----------------
__global__ __launch_bounds__(256) void qkv_mfma(
    const short* __restrict__ XB,
    const short* __restrict__ WT0, const short* __restrict__ WT1, const short* __restrict__ WT2,
    short* __restrict__ O0, short* __restrict__ O1, short* __restrict__ O2) {
  const int t = threadIdx.x, w = t >> 6, lane = t & 63, q = lane >> 4, m = lane & 15;
  const size_t row0 = (size_t)blockIdx.x * 64;
  const short* WT = (blockIdx.y == 0) ? WT0 : (blockIdx.y == 1) ? WT1 : WT2;
  short* O = (blockIdx.y == 0) ? O0 : (blockIdx.y == 1) ? O1 : O2;

  f32x4 acc[4][4];
#pragma unroll
  for (int i = 0; i < 4; ++i)
#pragma unroll
    for (int j = 0; j < 4; ++j) acc[i][j] = (f32x4){0.f, 0.f, 0.f, 0.f};

  const short* abase = XB + (row0 + m) * (size_t)256 + q * 8;
  const short* bbase = WT + (size_t)(w * 64 + m) * 256 + q * 8;
  bf16x8 a[4], b[4];
#pragma unroll
  for (int i = 0; i < 4; ++i) a[i] = *(const bf16x8*)(abase + (size_t)i * 4096);
#pragma unroll
  for (int j = 0; j < 4; ++j) b[j] = *(const bf16x8*)(bbase + (size_t)j * 4096);
#pragma unroll
  for (int kk = 0; kk < 8; ++kk) {
    bf16x8 an[4], bn[4];
    if (kk < 7) {
#pragma unroll
      for (int i = 0; i < 4; ++i) an[i] = *(const bf16x8*)(abase + (size_t)i * 4096 + (kk + 1) * 32);
#pragma unroll
      for (int j = 0; j < 4; ++j) bn[j] = *(const bf16x8*)(bbase + (size_t)j * 4096 + (kk + 1) * 32);
    }
#pragma unroll
    for (int i = 0; i < 4; ++i)
#pragma unroll
      for (int j = 0; j < 4; ++j)
        acc[i][j] = __builtin_amdgcn_mfma_f32_16x16x32_bf16(a[i], b[j], acc[i][j], 0, 0, 0);
    if (kk < 7) {
#pragma unroll
      for (int i = 0; i < 4; ++i) a[i] = an[i];
#pragma unroll
      for (int j = 0; j < 4; ++j) b[j] = bn[j];
    }
  }
#pragma unroll
  for (int i = 0; i < 4; ++i)
#pragma unroll
    for (int j = 0; j < 4; ++j)
#pragma unroll
      for (int r = 0; r < 4; ++r) {
        size_t row = row0 + i * 16 + q * 4 + r;
        int col = w * 64 + j * 16 + m;
        O[row * 256 + col] = f2bf(acc[i][j][r]);
      }
}

// ---------------- windowed attention v7 ----------------
// v6 -> v7: v6's late V-loads were HOISTED by the compiler above the unrolled
// score region (evidence: v6 codegen == v5 codegen: VGPR 128 both, FETCH/WRITE
// 305/563 vs 307/560 MB -- the compiler recreated v5's explicit prefetch and
// spilled sc[81] to scratch). __syncthreads() does not block upward motion of
// non-atomic loads. Fix: a compiler memory barrier (asm "" ::: "memory") +
// sched_barrier(0) at the phase flip makes the hoist illegal at IR and MIR
// level. Phase-1 peak pressure returns to R1's ~110 live regs.
// VERDICT COUNTER: VGPR ~120 + FETCH ~31 MB => theory right.
//                  VGPR 128 + FETCH ~300 MB => theory dead, revert to R1.
// NOTE: SQ_LDS_BANK_CONFLICT = 3538944 is IDENTICAL across all swizzles ->
// structural ds_read_b64 floor (512 B/wave vs 128 B/cy LDS). Closed axis.
__global__ __launch_bounds__(256, 2) void attn_kernel(
    const short* __restrict__ XQb, const short* __restrict__ XKb, const short* __restrict__ XVb,
    const short* __restrict__ PQb, const short* __restrict__ PKb, const short* __restrict__ PVb,
    short* __restrict__ CTXB) {
  __shared__ short sA[RSN * SST];   // phase1: Q   phase2: V
  __shared__ short sK[RSN * SST];   // K
  __shared__ short pA[WNN * PST];   // phase1: posQ  phase2: posV
  __shared__ short pK[WNN * PST];   // posK

  const int t = threadIdx.x;
  const int nblk = LL / CW;
  const int b = blockIdx.x / nblk;
  const int n0 = (blockIdx.x % nblk) * CW;
  const size_t base = (size_t)b * LL * DD;

  // staging lane->column mapping: lane lq writes physical slot lq of its row.
  // inverse of p(h,c): h = (lq&31)>>2, c = (lq&3) | ((lq>>5)<<2); logical
  // short4 index = h*8 + c.
  const int lq   = t & 63;
  const int sh_h = (lq & 31) >> 2;
  const int sh_c = (lq & 3) | ((lq >> 5) << 2);
  const int gcol = (sh_h * 8 + sh_c) * 4;   // logical short offset of this lane's short4
  const int pcol = lq * 4;                  // physical short offset (slot lq)

  // ---- stage Q,K halo rows ----
#pragma unroll
  for (int i = 0; i < RSN / 4; ++i) {   // 10 iters, one full row per wave
    int r = (t >> 6) + i * 4;
    int j = n0 - PPAD + r;
    short4 vq = {0, 0, 0, 0}, vk = vq;
    if (j >= 0 && j < LL) {
      size_t off = base + (size_t)j * DD + gcol;
      vq = *(const short4*)(XQb + off);
      vk = *(const short4*)(XKb + off);
    }
    *(short4*)&sA[r * SST + pcol] = vq;
    *(short4*)&sK[r * SST + pcol] = vk;
  }
#pragma unroll
  for (int i = 0; i < 3; ++i) {
    int r = (t >> 6) + i * 4;
    if (r < WNN) {
      *(short4*)&pA[r * PST + pcol] = *(const short4*)(PQb + r * DD + gcol);
      *(short4*)&pK[r * PST + pcol] = *(const short4*)(PKb + r * DD + gcol);
    }
  }
  __syncthreads();

  const int n = t >> 3;        // window within block
  const int h = t & 7;         // head
  const int hoff = h * HDIM;   // logical head offset (global writes only)

  float sc[WNN][WNN];
#pragma unroll
  for (int qi = 0; qi < WNN; ++qi)
#pragma unroll
    for (int ki = 0; ki < WNN; ++ki) sc[qi][ki] = 0.f;

  // scores: chunked K-dim so each q/k element is converted once, used 9x
#pragma unroll
  for (int c = 0; c < 8; ++c) {
    const int cph = h * 16 + (c & 3) * 4 + (c >> 2) * 128;  // physical short offset
    float qv[WNN][4], kv[WNN][4];
#pragma unroll
    for (int r = 0; r < WNN; ++r) {
      short4 xa = *(const short4*)&sA[(n + r) * SST + cph];
      short4 pa = *(const short4*)&pA[r * PST + cph];
      qv[r][0] = bf2f(xa.x) + bf2f(pa.x);
      qv[r][1] = bf2f(xa.y) + bf2f(pa.y);
      qv[r][2] = bf2f(xa.z) + bf2f(pa.z);
      qv[r][3] = bf2f(xa.w) + bf2f(pa.w);
      short4 xb = *(const short4*)&sK[(n + r) * SST + cph];
      short4 pb = *(const short4*)&pK[r * PST + cph];
      kv[r][0] = bf2f(xb.x) + bf2f(pb.x);
      kv[r][1] = bf2f(xb.y) + bf2f(pb.y);
      kv[r][2] = bf2f(xb.z) + bf2f(pb.z);
      kv[r][3] = bf2f(xb.w) + bf2f(pb.w);
    }
#pragma unroll
    for (int qi = 0; qi < WNN; ++qi)
#pragma unroll
      for (int ki = 0; ki < WNN; ++ki)
        sc[qi][ki] += qv[qi][0] * kv[ki][0] + qv[qi][1] * kv[ki][1] +
                      qv[qi][2] * kv[ki][2] + qv[qi][3] * kv[ki][3];
  }

  // softmax per q-row, accumulate column sums (all thread-local)
  float cs[WNN];
#pragma unroll
  for (int ki = 0; ki < WNN; ++ki) cs[ki] = 0.f;
  const float scale = 0.17677669529663687f;  // 1/sqrt(32)
#pragma unroll
  for (int qi = 0; qi < WNN; ++qi) {
    float mx = sc[qi][0];
#pragma unroll
    for (int ki = 1; ki < WNN; ++ki) mx = fmaxf(mx, sc[qi][ki]);
    float e[WNN], sum = 0.f;
#pragma unroll
    for (int ki = 0; ki < WNN; ++ki) { e[ki] = __expf((sc[qi][ki] - mx) * scale); sum += e[ki]; }
    float inv = 1.f / sum;
#pragma unroll
    for (int ki = 0; ki < WNN; ++ki) cs[ki] += e[ki] * inv;
  }

  // ---- phase flip: load V fresh from global, write into Q's buffer ----
  __syncthreads();                      // all phase-1 reads of sA/pA done
  // HARD FENCE: forbid the compiler from hoisting the V loads above the
  // score region (the v5/v6 spill cause). asm memory clobber blocks IR-level
  // motion; sched_barrier(0) blocks the machine scheduler.
  asm volatile("" ::: "memory");
  __builtin_amdgcn_sched_barrier(0);
#pragma unroll
  for (int i = 0; i < RSN / 4; ++i) {
    int r = (t >> 6) + i * 4;
    int j = n0 - PPAD + r;
    short4 vv = {0, 0, 0, 0};
    if (j >= 0 && j < LL) vv = *(const short4*)(XVb + base + (size_t)j * DD + gcol);
    *(short4*)&sA[r * SST + pcol] = vv;
  }
#pragma unroll
  for (int i = 0; i < 3; ++i) {
    int r = (t >> 6) + i * 4;
    if (r < WNN) *(short4*)&pA[r * PST + pcol] = *(const short4*)(PVb + r * DD + gcol);
  }
  __syncthreads();

  // ctx: weighted sum of v rows (+ pos-v), write bf16 (global layout unchanged)
#pragma unroll
  for (int c = 0; c < 8; ++c) {
    const int cph = h * 16 + (c & 3) * 4 + (c >> 2) * 128;
    float o0 = 0.f, o1 = 0.f, o2 = 0.f, o3 = 0.f;
#pragma unroll
    for (int ki = 0; ki < WNN; ++ki) {
      short4 xv4 = *(const short4*)&sA[(n + ki) * SST + cph];
      short4 pv4 = *(const short4*)&pA[ki * PST + cph];
      float wt = cs[ki];
      o0 += wt * (bf2f(xv4.x) + bf2f(pv4.x));
      o1 += wt * (bf2f(xv4.y) + bf2f(pv4.y));
      o2 += wt * (bf2f(xv4.z) + bf2f(pv4.z));
      o3 += wt * (bf2f(xv4.w) + bf2f(pv4.w));
    }
    short4 os; os.x = f2bf(o0); os.y = f2bf(o1); os.z = f2bf(o2); os.w = f2bf(o3);
    *(short4*)(CTXB + base + (size_t)(n0 + n) * DD + hoff + c * 4) = os;
  }
}

// CAUTION: softmax scale note — reference scales scores BEFORE softmax; we fold
// the scale into the exp argument ((sc-mx)*scale) which is equivalent since mx
// is the max of unscaled scores and scale>0.

// ---------------- fused out stage via MFMA ----------------
__global__ __launch_bounds__(256) void out_mfma(
    const short* __restrict__ CTXB, const float* __restrict__ X,
    const short* __restrict__ WoT, const short* __restrict__ WoutB,
    const float* __restrict__ bo,
    const float* __restrict__ g1, const float* __restrict__ b1,
    const float* __restrict__ g2, const float* __restrict__ b2,
    float* __restrict__ out) {
  __shared__ short ar[64 * 264];
  __shared__ float ws1[64][4], ws2[64][4];
  __shared__ float msh[64], rsh[64];
  __shared__ float g1s[256], b1s[256], g2s[256], b2s[256], bos[256];
  const int t = threadIdx.x, w = t >> 6, lane = t & 63, q = lane >> 4, m = lane & 15;
  const size_t row0 = (size_t)blockIdx.x * 64;
  g1s[t] = g1[t]; b1s[t] = b1[t]; g2s[t] = g2[t]; b2s[t] = b2[t]; bos[t] = bo[t];

  f32x4 acc[4][4];
#pragma unroll
  for (int i = 0; i < 4; ++i)
#pragma unroll
    for (int j = 0; j < 4; ++j) acc[i][j] = (f32x4){0.f, 0.f, 0.f, 0.f};

  // GEMM1: ctx @ Wo (register-dbuf prefetch)
  const short* abase = CTXB + (row0 + m) * (size_t)256 + q * 8;
  const short* bbase = WoT + (size_t)(w * 64 + m) * 256 + q * 8;
  {
    bf16x8 a[4], b[4];
#pragma unroll
    for (int i = 0; i < 4; ++i) a[i] = *(const bf16x8*)(abase + (size_t)i * 4096);
#pragma unroll
    for (int j = 0; j < 4; ++j) b[j] = *(const bf16x8*)(bbase + (size_t)j * 4096);
#pragma unroll
    for (int kk = 0; kk < 8; ++kk) {
      bf16x8 an[4], bn[4];
      if (kk < 7) {
#pragma unroll
        for (int i = 0; i < 4; ++i) an[i] = *(const bf16x8*)(abase + (size_t)i * 4096 + (kk + 1) * 32);
#pragma unroll
        for (int j = 0; j < 4; ++j) bn[j] = *(const bf16x8*)(bbase + (size_t)j * 4096 + (kk + 1) * 32);
      }
#pragma unroll
      for (int i = 0; i < 4; ++i)
#pragma unroll
        for (int j = 0; j < 4; ++j)
          acc[i][j] = __builtin_amdgcn_mfma_f32_16x16x32_bf16(a[i], b[j], acc[i][j], 0, 0, 0);
      if (kk < 7) {
#pragma unroll
        for (int i = 0; i < 4; ++i) a[i] = an[i];
#pragma unroll
        for (int j = 0; j < 4; ++j) b[j] = bn[j];
      }
    }
  }

  // + skip, LN1 partial stats
  float s1v[4][4], s2v[4][4];
#pragma unroll
  for (int i = 0; i < 4; ++i)
#pragma unroll
    for (int r = 0; r < 4; ++r) {
      float a0 = 0.f, b0 = 0.f;
#pragma unroll
      for (int j = 0; j < 4; ++j) {
        float v = acc[i][j][r] + X[(row0 + i * 16 + q * 4 + r) * 256 + w * 64 + j * 16 + m];
        acc[i][j][r] = v; a0 += v; b0 += v * v;
      }
      s1v[i][r] = a0; s2v[i][r] = b0;
    }
#pragma unroll
  for (int i = 0; i < 4; ++i)
#pragma unroll
    for (int r = 0; r < 4; ++r)
#pragma unroll
      for (int msk = 1; msk < 16; msk <<= 1) {
        s1v[i][r] += __shfl_xor(s1v[i][r], msk, 64);
        s2v[i][r] += __shfl_xor(s2v[i][r], msk, 64);
      }
  if (m == 0) {
#pragma unroll
    for (int i = 0; i < 4; ++i)
#pragma unroll
      for (int r = 0; r < 4; ++r) {
        ws1[i * 16 + q * 4 + r][w] = s1v[i][r];
        ws2[i * 16 + q * 4 + r][w] = s2v[i][r];
      }
  }
  __syncthreads();
  if (t < 64) {
    float a0 = 0.f, b0 = 0.f;
#pragma unroll
    for (int ww = 0; ww < 4; ++ww) { a0 += ws1[t][ww]; b0 += ws2[t][ww]; }
    float mean = a0 * (1.f / 256.f);
    float var = b0 * (1.f / 256.f) - mean * mean;
    msh[t] = mean; rsh[t] = rsqrtf(var + 1e-5f);
  }
  __syncthreads();

#pragma unroll
  for (int i = 0; i < 4; ++i)
#pragma unroll
    for (int r = 0; r < 4; ++r) {
      int row = i * 16 + q * 4 + r;
      float mean = msh[row], rst = rsh[row];
#pragma unroll
      for (int j = 0; j < 4; ++j) {
        int col = w * 64 + j * 16 + m;
        float v = (acc[i][j][r] - mean) * rst * g1s[col] + b1s[col];
        ar[row * 264 + col] = f2bf(v);
      }
    }
  __syncthreads();

  // GEMM2: ar @ Wout^T (A from LDS, B global with prefetch)
#pragma unroll
  for (int i = 0; i < 4; ++i)
#pragma unroll
    for (int j = 0; j < 4; ++j) acc[i][j] = (f32x4){0.f, 0.f, 0.f, 0.f};
  const short* b2base = WoutB + (size_t)(w * 64 + m) * 256 + q * 8;
  {
    bf16x8 b[4];
#pragma unroll
    for (int j = 0; j < 4; ++j) b[j] = *(const bf16x8*)(b2base + (size_t)j * 4096);
#pragma unroll
    for (int kk = 0; kk < 8; ++kk) {
      bf16x8 bn[4];
      if (kk < 7) {
#pragma unroll
        for (int j = 0; j < 4; ++j) bn[j] = *(const bf16x8*)(b2base + (size_t)j * 4096 + (kk + 1) * 32);
      }
      bf16x8 a[4];
#pragma unroll
      for (int i = 0; i < 4; ++i) a[i] = *(const bf16x8*)&ar[(i * 16 + m) * 264 + kk * 32 + q * 8];
#pragma unroll
      for (int i = 0; i < 4; ++i)
#pragma unroll
        for (int j = 0; j < 4; ++j)
          acc[i][j] = __builtin_amdgcn_mfma_f32_16x16x32_bf16(a[i], b[j], acc[i][j], 0, 0, 0);
      if (kk < 7) {
#pragma unroll
        for (int j = 0; j < 4; ++j) b[j] = bn[j];
      }
    }
  }

  // + bias + residual, LN2 stats
#pragma unroll
  for (int i = 0; i < 4; ++i)
#pragma unroll
    for (int r = 0; r < 4; ++r) {
      int row = i * 16 + q * 4 + r;
      float a0 = 0.f, b0 = 0.f;
#pragma unroll
      for (int j = 0; j < 4; ++j) {
        int col = w * 64 + j * 16 + m;
        float v = acc[i][j][r] + bos[col] + bf2f(ar[row * 264 + col]);
        acc[i][j][r] = v; a0 += v; b0 += v * v;
      }
      s1v[i][r] = a0; s2v[i][r] = b0;
    }
#pragma unroll
  for (int i = 0; i < 4; ++i)
#pragma unroll
    for (int r = 0; r < 4; ++r)
#pragma unroll
      for (int msk = 1; msk < 16; msk <<= 1) {
        s1v[i][r] += __shfl_xor(s1v[i][r], msk, 64);
        s2v[i][r] += __shfl_xor(s2v[i][r], msk, 64);
      }
  if (m == 0) {
#pragma unroll
    for (int i = 0; i < 4; ++i)
#pragma unroll
      for (int r = 0; r < 4; ++r) {
        ws1[i * 16 + q * 4 + r][w] = s1v[i][r];
        ws2[i * 16 + q * 4 + r][w] = s2v[i][r];
      }
  }
  __syncthreads();
  if (t < 64) {
    float a0 = 0.f, b0 = 0.f;
#pragma unroll
    for (int ww = 0; ww < 4; ++ww) { a0 += ws1[t][ww]; b0 += ws2[t][ww]; }
    float mean = a0 * (1.f / 256.f);
    float var = b0 * (1.f / 256.f) - mean * mean;
    msh[t] = mean; rsh[t] = rsqrtf(var + 1e-5f);
  }
  __syncthreads();

#pragma unroll
  for (int i = 0; i < 4; ++i)
#pragma unroll
    for (int r = 0; r < 4; ++r) {
      int row = i * 16 + q * 4 + r;
      float mean = msh[row], rst = rsh[row];
#pragma unroll
      for (int j = 0; j < 4; ++j) {
        int col = w * 64 + j * 16 + m;
        float v = (acc[i][j][r] - mean) * rst * g2s[col] + b2s[col];
        out[(row0 + row) * 256 + col] = fmaxf(v, 0.f);
      }
    }
}

extern "C" void kernel_launch(void* const* d_in, const int* in_sizes, int n_in,
                              void* d_out, int out_size, void* d_ws, size_t ws_size,
                              hipStream_t stream) {
  const float* x    = (const float*)d_in[0];
  const float* Wq   = (const float*)d_in[1];
  const float* Wk   = (const float*)d_in[2];
  const float* Wv   = (const float*)d_in[3];
  const float* Wo   = (const float*)d_in[4];
  const float* pos  = (const float*)d_in[5];
  const float* Wout = (const float*)d_in[6];
  const float* bo   = (const float*)d_in[7];
  const float* g1   = (const float*)d_in[8];
  const float* b1   = (const float*)d_in[9];
  const float* g2   = (const float*)d_in[10];
  const float* b2   = (const float*)d_in[11];
  float* out = (float*)d_out;

  const size_t nel = (size_t)NB * LL * DD;
  char* wsb = (char*)d_ws;
  short* XB   = (short*)wsb; wsb += nel * 2;
  short* XQb  = (short*)wsb; wsb += nel * 2;
  short* XKb  = (short*)wsb; wsb += nel * 2;
  short* XVb  = (short*)wsb; wsb += nel * 2;
  short* CTXB = (short*)wsb; wsb += nel * 2;
  short* WqT   = (short*)wsb; wsb += 65536 * 2;
  short* WkT   = (short*)wsb; wsb += 65536 * 2;
  short* WvT   = (short*)wsb; wsb += 65536 * 2;
  short* WoT   = (short*)wsb; wsb += 65536 * 2;
  short* WoutB = (short*)wsb; wsb += 65536 * 2;
  short* PQb = (short*)wsb; wsb += WNN * DD * 2;
  short* PKb = (short*)wsb; wsb += WNN * DD * 2;
  short* PVb = (short*)wsb; wsb += WNN * DD * 2;

  conv_x<<<(unsigned)(nel / 4 / 256), 256, 0, stream>>>(x, XB);
  prep_w<<<5, 256, 0, stream>>>(Wq, Wk, Wv, Wo, Wout, WqT, WkT, WvT, WoT, WoutB);
  pos_proj<<<dim3(WNN, 3), 256, 0, stream>>>(pos, Wq, Wk, Wv, PQb, PKb, PVb);
  qkv_mfma<<<dim3((unsigned)(NB * LL / 64), 3), 256, 0, stream>>>(XB, WqT, WkT, WvT, XQb, XKb, XVb);
  attn_kernel<<<NB * (LL / CW), 256, 0, stream>>>(XQb, XKb, XVb, PQb, PKb, PVb, CTXB);
  out_mfma<<<(unsigned)(NB * LL / 64), 256, 0, stream>>>(CTXB, x, WoT, WoutB, bo, g1, b1, g2, b2, out);
}

// Round 6
// 257.803 us; speedup vs baseline: 1.9921x; 1.9711x over previous
//
#include <hip/hip_runtime.h>
#include <hip/hip_bf16.h>
#include <math.h>

constexpr int NB   = 4;
constexpr int LL   = 8192;
constexpr int DD   = 256;
constexpr int NH   = 8;
constexpr int HDIM = 32;
constexpr int WNN  = 9;
constexpr int PPAD = 4;

constexpr int CW  = 32;         // windows per attention block
constexpr int RSN = CW + 8;     // 40 staged rows
constexpr int SST = 260;        // bf16 LDS row stride (65 8B-slots, odd -> row spread)

typedef __attribute__((ext_vector_type(8))) short bf16x8;
typedef __attribute__((ext_vector_type(4))) float f32x4;

__device__ inline short f2bf(float f) {
  __hip_bfloat16 h = __float2bfloat16(f);
  short s; __builtin_memcpy(&s, &h, 2); return s;
}
__device__ inline float bf2f(short s) {
  unsigned u = ((unsigned)(unsigned short)s) << 16;
  float f; __builtin_memcpy(&f, &u, 4); return f;
}

// ---------------- merged prep: prep_w (bx 0..4) | pos_proj (bx 5..31) | conv_x (bx 32..8223) ----------------
// conv_x / prep_w / pos_proj are mutually independent; merging removes 2 launch
// serialization gaps and fills the GPU during the tiny prep blocks (prep_w = 5
// blocks, pos_proj = 27 blocks -> >99% idle when run as standalone launches).
// Small latency-bound blocks dispatch FIRST so they start earliest.
__global__ __launch_bounds__(256) void prep_all(
    const float* __restrict__ x, short* __restrict__ XB,
    const float* __restrict__ Wq, const float* __restrict__ Wk, const float* __restrict__ Wv,
    const float* __restrict__ Wo, const float* __restrict__ Wout,
    short* __restrict__ WqT, short* __restrict__ WkT, short* __restrict__ WvT,
    short* __restrict__ WoT, short* __restrict__ WoutB,
    const float* __restrict__ pos,
    short* __restrict__ PQb, short* __restrict__ PKb, short* __restrict__ PVb) {
  __shared__ float ps[256];
  const int t = threadIdx.x;
  const int bx = blockIdx.x;
  if (bx < 4) {
    // --- prep_w: transpose Wq/Wk/Wv/Wo -> bf16 n-major ---
    const float* W = (bx == 0) ? Wq : (bx == 1) ? Wk : (bx == 2) ? Wv : Wo;
    short* T = (bx == 0) ? WqT : (bx == 1) ? WkT : (bx == 2) ? WvT : WoT;
    for (int k = 0; k < 256; k += 4) {
      short4 o;
      o.x = f2bf(W[(size_t)(k + 0) * 256 + t]);
      o.y = f2bf(W[(size_t)(k + 1) * 256 + t]);
      o.z = f2bf(W[(size_t)(k + 2) * 256 + t]);
      o.w = f2bf(W[(size_t)(k + 3) * 256 + t]);
      *(short4*)&T[(size_t)t * 256 + k] = o;
    }
  } else if (bx == 4) {
    // --- prep_w: Wout -> bf16 straight ---
    for (int i = t; i < 16384; i += 256) {
      float4 v = *(const float4*)(Wout + (size_t)i * 4);
      short4 o; o.x = f2bf(v.x); o.y = f2bf(v.y); o.z = f2bf(v.z); o.w = f2bf(v.w);
      *(short4*)(WoutB + (size_t)i * 4) = o;
    }
  } else if (bx < 32) {
    // --- pos_proj: 27 blocks = (wrow 0..8) x (wh 0..2) ---
    const int idx = bx - 5;
    const int wrow = idx % WNN, wh = idx / WNN;
    const float* W = (wh == 0) ? Wq : (wh == 1) ? Wk : Wv;
    short* P = (wh == 0) ? PQb : (wh == 1) ? PKb : PVb;
    ps[t] = pos[wrow * 256 + t];
    __syncthreads();
    float a = 0.f;
    for (int d = 0; d < 256; ++d) a += ps[d] * W[(size_t)d * 256 + t];
    P[wrow * 256 + t] = f2bf(a);
  } else {
    // --- conv_x: x -> bf16, 8192 blocks ---
    size_t i = ((size_t)(bx - 32) * 256 + t) * 4;
    float4 v = *(const float4*)(x + i);
    short4 o; o.x = f2bf(v.x); o.y = f2bf(v.y); o.z = f2bf(v.z); o.w = f2bf(v.w);
    *(short4*)(XB + i) = o;
  }
}

// ---------------- QKV projection via MFMA with register-dbuf prefetch ----------------
__global__ __launch_bounds__(256) void qkv_mfma(
    const short* __restrict__ XB,
    const short* __restrict__ WT0, const short* __restrict__ WT1, const short* __restrict__ WT2,
    short* __restrict__ O0, short* __restrict__ O1, short* __restrict__ O2) {
  const int t = threadIdx.x, w = t >> 6, lane = t & 63, q = lane >> 4, m = lane & 15;
  const size_t row0 = (size_t)blockIdx.x * 64;
  const short* WT = (blockIdx.y == 0) ? WT0 : (blockIdx.y == 1) ? WT1 : WT2;
  short* O = (blockIdx.y == 0) ? O0 : (blockIdx.y == 1) ? O1 : O2;

  f32x4 acc[4][4];
#pragma unroll
  for (int i = 0; i < 4; ++i)
#pragma unroll
    for (int j = 0; j < 4; ++j) acc[i][j] = (f32x4){0.f, 0.f, 0.f, 0.f};

  const short* abase = XB + (row0 + m) * (size_t)256 + q * 8;
  const short* bbase = WT + (size_t)(w * 64 + m) * 256 + q * 8;
  bf16x8 a[4], b[4];
#pragma unroll
  for (int i = 0; i < 4; ++i) a[i] = *(const bf16x8*)(abase + (size_t)i * 4096);
#pragma unroll
  for (int j = 0; j < 4; ++j) b[j] = *(const bf16x8*)(bbase + (size_t)j * 4096);
#pragma unroll
  for (int kk = 0; kk < 8; ++kk) {
    bf16x8 an[4], bn[4];
    if (kk < 7) {
#pragma unroll
      for (int i = 0; i < 4; ++i) an[i] = *(const bf16x8*)(abase + (size_t)i * 4096 + (kk + 1) * 32);
#pragma unroll
      for (int j = 0; j < 4; ++j) bn[j] = *(const bf16x8*)(bbase + (size_t)j * 4096 + (kk + 1) * 32);
    }
#pragma unroll
    for (int i = 0; i < 4; ++i)
#pragma unroll
      for (int j = 0; j < 4; ++j)
        acc[i][j] = __builtin_amdgcn_mfma_f32_16x16x32_bf16(a[i], b[j], acc[i][j], 0, 0, 0);
    if (kk < 7) {
#pragma unroll
      for (int i = 0; i < 4; ++i) a[i] = an[i];
#pragma unroll
      for (int j = 0; j < 4; ++j) b[j] = bn[j];
    }
  }
#pragma unroll
  for (int i = 0; i < 4; ++i)
#pragma unroll
    for (int j = 0; j < 4; ++j)
#pragma unroll
      for (int r = 0; r < 4; ++r) {
        size_t row = row0 + i * 16 + q * 4 + r;
        int col = w * 64 + j * 16 + m;
        O[row * 256 + col] = f2bf(acc[i][j][r]);
      }
}

// ---------------- windowed attention (R1 kernel, EXACT revert) ----------------
// HISTORY: R1 = 60.2 us, VGPR 120, FETCH 31 MB, no spill. R2-R5 tried a 51 KB
// LDS overlay (V into Q's buffer) for 3 blocks/CU; natural VGPR demand rose to
// ~150 and the AMDGPU allocator CLAMPED to the 128 occupancy step and spilled
// sc[] in-loop (~850 MB/dispatch scratch traffic, 277-470 us) -- in BOTH
// launch_bounds (256,3)->84 and (256,2)->128, with and without load fences.
// Lesson: the allocator spills to meet its occupancy target; any structure
// whose unrolled peak exceeds the next 64/128/256 step regresses massively.
// The overlay axis is closed. SQ_LDS_BANK_CONFLICT = 3538944 is the
// structural ds_read_b64 floor (identical across 3 swizzles). Closed axis.
__global__ __launch_bounds__(256, 2) void attn_kernel(
    const short* __restrict__ XQb, const short* __restrict__ XKb, const short* __restrict__ XVb,
    const short* __restrict__ PQb, const short* __restrict__ PKb, const short* __restrict__ PVb,
    short* __restrict__ CTXB) {
  __shared__ short sq[RSN * SST];
  __shared__ short sk[RSN * SST];
  __shared__ short sv[RSN * SST];
  __shared__ short pq[WNN * SST];
  __shared__ short pk[WNN * SST];
  __shared__ short pv[WNN * SST];

  const int t = threadIdx.x;
  const int nblk = LL / CW;
  const int b = blockIdx.x / nblk;
  const int n0 = (blockIdx.x % nblk) * CW;
  const size_t base = (size_t)b * LL * DD;

  // lane->column mapping for staging: group g = ((lane&7)<<3)|(lane>>3) so that
  // the physical LDS write slot is r*65 + lane (conflict-free), while global
  // reads still cover each 64B segment exactly (permuted within the wave).
  const int lq   = t & 63;
  const int gcol = ((((lq & 7) << 3) | (lq >> 3))) * 4;   // global short offset of this lane's short4
  const int pcol = ((lq >> 3) << 5) | ((lq & 7) << 2);    // physical LDS short offset

  // stage 40 halo rows of XQ/XK/XV (bf16, vectorized, coalesced)
#pragma unroll
  for (int i = 0; i < RSN / 4; ++i) {   // 10 iters, one full row per wave
    int r = (t >> 6) + i * 4;
    int j = n0 - PPAD + r;
    short4 vq = {0, 0, 0, 0}, vk = vq, vv = vq;
    if (j >= 0 && j < LL) {
      size_t off = base + (size_t)j * DD + gcol;
      vq = *(const short4*)(XQb + off);
      vk = *(const short4*)(XKb + off);
      vv = *(const short4*)(XVb + off);
    }
    *(short4*)&sq[r * SST + pcol] = vq;
    *(short4*)&sk[r * SST + pcol] = vk;
    *(short4*)&sv[r * SST + pcol] = vv;
  }
  // stage pos projections (9 rows), same interleaved layout
#pragma unroll
  for (int i = 0; i < 3; ++i) {
    int r = (t >> 6) + i * 4;
    if (r < WNN) {
      *(short4*)&pq[r * SST + pcol] = *(const short4*)(PQb + r * DD + gcol);
      *(short4*)&pk[r * SST + pcol] = *(const short4*)(PKb + r * DD + gcol);
      *(short4*)&pv[r * SST + pcol] = *(const short4*)(PVb + r * DD + gcol);
    }
  }
  __syncthreads();

  const int n = t >> 3;        // window within block
  const int h = t & 7;         // head
  const int hoff = h * HDIM;   // logical head offset (used for global writes only)
  const int hph = h * 4;       // physical head offset within a 32-short chunk

  float sc[WNN][WNN];
#pragma unroll
  for (int qi = 0; qi < WNN; ++qi)
#pragma unroll
    for (int ki = 0; ki < WNN; ++ki) sc[qi][ki] = 0.f;

  // scores: chunked K-dim so each q/k element is converted once, used 9x
#pragma unroll
  for (int c = 0; c < 8; ++c) {
    const int cph = c * 32 + hph;   // physical column of this (h, c) short4
    float qv[WNN][4], kv[WNN][4];
#pragma unroll
    for (int r = 0; r < WNN; ++r) {
      short4 xa = *(const short4*)&sq[(n + r) * SST + cph];
      short4 pa = *(const short4*)&pq[r * SST + cph];
      qv[r][0] = bf2f(xa.x) + bf2f(pa.x);
      qv[r][1] = bf2f(xa.y) + bf2f(pa.y);
      qv[r][2] = bf2f(xa.z) + bf2f(pa.z);
      qv[r][3] = bf2f(xa.w) + bf2f(pa.w);
      short4 xb = *(const short4*)&sk[(n + r) * SST + cph];
      short4 pb = *(const short4*)&pk[r * SST + cph];
      kv[r][0] = bf2f(xb.x) + bf2f(pb.x);
      kv[r][1] = bf2f(xb.y) + bf2f(pb.y);
      kv[r][2] = bf2f(xb.z) + bf2f(pb.z);
      kv[r][3] = bf2f(xb.w) + bf2f(pb.w);
    }
#pragma unroll
    for (int qi = 0; qi < WNN; ++qi)
#pragma unroll
      for (int ki = 0; ki < WNN; ++ki)
        sc[qi][ki] += qv[qi][0] * kv[ki][0] + qv[qi][1] * kv[ki][1] +
                      qv[qi][2] * kv[ki][2] + qv[qi][3] * kv[ki][3];
  }

  // softmax per q-row, accumulate column sums (all thread-local)
  float cs[WNN];
#pragma unroll
  for (int ki = 0; ki < WNN; ++ki) cs[ki] = 0.f;
  const float scale = 0.17677669529663687f;  // 1/sqrt(32)
#pragma unroll
  for (int qi = 0; qi < WNN; ++qi) {
    float mx = sc[qi][0];
#pragma unroll
    for (int ki = 1; ki < WNN; ++ki) mx = fmaxf(mx, sc[qi][ki]);
    float e[WNN], sum = 0.f;
#pragma unroll
    for (int ki = 0; ki < WNN; ++ki) { e[ki] = __expf((sc[qi][ki] - mx) * scale); sum += e[ki]; }
    float inv = 1.f / sum;
#pragma unroll
    for (int ki = 0; ki < WNN; ++ki) cs[ki] += e[ki] * inv;
  }

  // ctx: weighted sum of v rows (+ pos-v), write bf16 (global layout unchanged)
#pragma unroll
  for (int c = 0; c < 8; ++c) {
    const int cph = c * 32 + hph;
    float o0 = 0.f, o1 = 0.f, o2 = 0.f, o3 = 0.f;
#pragma unroll
    for (int ki = 0; ki < WNN; ++ki) {
      short4 xv4 = *(const short4*)&sv[(n + ki) * SST + cph];
      short4 pv4 = *(const short4*)&pv[ki * SST + cph];
      float wt = cs[ki];
      o0 += wt * (bf2f(xv4.x) + bf2f(pv4.x));
      o1 += wt * (bf2f(xv4.y) + bf2f(pv4.y));
      o2 += wt * (bf2f(xv4.z) + bf2f(pv4.z));
      o3 += wt * (bf2f(xv4.w) + bf2f(pv4.w));
    }
    short4 os; os.x = f2bf(o0); os.y = f2bf(o1); os.z = f2bf(o2); os.w = f2bf(o3);
    *(short4*)(CTXB + base + (size_t)(n0 + n) * DD + hoff + c * 4) = os;
  }
}

// CAUTION: softmax scale note — reference scales scores BEFORE softmax; we fold
// the scale into the exp argument ((sc-mx)*scale) which is equivalent since mx
// is the max of unscaled scores and scale>0.

// ---------------- fused out stage via MFMA ----------------
__global__ __launch_bounds__(256) void out_mfma(
    const short* __restrict__ CTXB, const float* __restrict__ X,
    const short* __restrict__ WoT, const short* __restrict__ WoutB,
    const float* __restrict__ bo,
    const float* __restrict__ g1, const float* __restrict__ b1,
    const float* __restrict__ g2, const float* __restrict__ b2,
    float* __restrict__ out) {
  __shared__ short ar[64 * 264];
  __shared__ float ws1[64][4], ws2[64][4];
  __shared__ float msh[64], rsh[64];
  __shared__ float g1s[256], b1s[256], g2s[256], b2s[256], bos[256];
  const int t = threadIdx.x, w = t >> 6, lane = t & 63, q = lane >> 4, m = lane & 15;
  const size_t row0 = (size_t)blockIdx.x * 64;
  g1s[t] = g1[t]; b1s[t] = b1[t]; g2s[t] = g2[t]; b2s[t] = b2[t]; bos[t] = bo[t];

  f32x4 acc[4][4];
#pragma unroll
  for (int i = 0; i < 4; ++i)
#pragma unroll
    for (int j = 0; j < 4; ++j) acc[i][j] = (f32x4){0.f, 0.f, 0.f, 0.f};

  // GEMM1: ctx @ Wo (register-dbuf prefetch)
  const short* abase = CTXB + (row0 + m) * (size_t)256 + q * 8;
  const short* bbase = WoT + (size_t)(w * 64 + m) * 256 + q * 8;
  {
    bf16x8 a[4], b[4];
#pragma unroll
    for (int i = 0; i < 4; ++i) a[i] = *(const bf16x8*)(abase + (size_t)i * 4096);
#pragma unroll
    for (int j = 0; j < 4; ++j) b[j] = *(const bf16x8*)(bbase + (size_t)j * 4096);
#pragma unroll
    for (int kk = 0; kk < 8; ++kk) {
      bf16x8 an[4], bn[4];
      if (kk < 7) {
#pragma unroll
        for (int i = 0; i < 4; ++i) an[i] = *(const bf16x8*)(abase + (size_t)i * 4096 + (kk + 1) * 32);
#pragma unroll
        for (int j = 0; j < 4; ++j) bn[j] = *(const bf16x8*)(bbase + (size_t)j * 4096 + (kk + 1) * 32);
      }
#pragma unroll
      for (int i = 0; i < 4; ++i)
#pragma unroll
        for (int j = 0; j < 4; ++j)
          acc[i][j] = __builtin_amdgcn_mfma_f32_16x16x32_bf16(a[i], b[j], acc[i][j], 0, 0, 0);
      if (kk < 7) {
#pragma unroll
        for (int i = 0; i < 4; ++i) a[i] = an[i];
#pragma unroll
        for (int j = 0; j < 4; ++j) b[j] = bn[j];
      }
    }
  }

  // + skip, LN1 partial stats
  float s1v[4][4], s2v[4][4];
#pragma unroll
  for (int i = 0; i < 4; ++i)
#pragma unroll
    for (int r = 0; r < 4; ++r) {
      float a0 = 0.f, b0 = 0.f;
#pragma unroll
      for (int j = 0; j < 4; ++j) {
        float v = acc[i][j][r] + X[(row0 + i * 16 + q * 4 + r) * 256 + w * 64 + j * 16 + m];
        acc[i][j][r] = v; a0 += v; b0 += v * v;
      }
      s1v[i][r] = a0; s2v[i][r] = b0;
    }
#pragma unroll
  for (int i = 0; i < 4; ++i)
#pragma unroll
    for (int r = 0; r < 4; ++r)
#pragma unroll
      for (int msk = 1; msk < 16; msk <<= 1) {
        s1v[i][r] += __shfl_xor(s1v[i][r], msk, 64);
        s2v[i][r] += __shfl_xor(s2v[i][r], msk, 64);
      }
  if (m == 0) {
#pragma unroll
    for (int i = 0; i < 4; ++i)
#pragma unroll
      for (int r = 0; r < 4; ++r) {
        ws1[i * 16 + q * 4 + r][w] = s1v[i][r];
        ws2[i * 16 + q * 4 + r][w] = s2v[i][r];
      }
  }
  __syncthreads();
  if (t < 64) {
    float a0 = 0.f, b0 = 0.f;
#pragma unroll
    for (int ww = 0; ww < 4; ++ww) { a0 += ws1[t][ww]; b0 += ws2[t][ww]; }
    float mean = a0 * (1.f / 256.f);
    float var = b0 * (1.f / 256.f) - mean * mean;
    msh[t] = mean; rsh[t] = rsqrtf(var + 1e-5f);
  }
  __syncthreads();

#pragma unroll
  for (int i = 0; i < 4; ++i)
#pragma unroll
    for (int r = 0; r < 4; ++r) {
      int row = i * 16 + q * 4 + r;
      float mean = msh[row], rst = rsh[row];
#pragma unroll
      for (int j = 0; j < 4; ++j) {
        int col = w * 64 + j * 16 + m;
        float v = (acc[i][j][r] - mean) * rst * g1s[col] + b1s[col];
        ar[row * 264 + col] = f2bf(v);
      }
    }
  __syncthreads();

  // GEMM2: ar @ Wout^T (A from LDS, B global with prefetch)
#pragma unroll
  for (int i = 0; i < 4; ++i)
#pragma unroll
    for (int j = 0; j < 4; ++j) acc[i][j] = (f32x4){0.f, 0.f, 0.f, 0.f};
  const short* b2base = WoutB + (size_t)(w * 64 + m) * 256 + q * 8;
  {
    bf16x8 b[4];
#pragma unroll
    for (int j = 0; j < 4; ++j) b[j] = *(const bf16x8*)(b2base + (size_t)j * 4096);
#pragma unroll
    for (int kk = 0; kk < 8; ++kk) {
      bf16x8 bn[4];
      if (kk < 7) {
#pragma unroll
        for (int j = 0; j < 4; ++j) bn[j] = *(const bf16x8*)(b2base + (size_t)j * 4096 + (kk + 1) * 32);
      }
      bf16x8 a[4];
#pragma unroll
      for (int i = 0; i < 4; ++i) a[i] = *(const bf16x8*)&ar[(i * 16 + m) * 264 + kk * 32 + q * 8];
#pragma unroll
      for (int i = 0; i < 4; ++i)
#pragma unroll
        for (int j = 0; j < 4; ++j)
          acc[i][j] = __builtin_amdgcn_mfma_f32_16x16x32_bf16(a[i], b[j], acc[i][j], 0, 0, 0);
      if (kk < 7) {
#pragma unroll
        for (int j = 0; j < 4; ++j) b[j] = bn[j];
      }
    }
  }

  // + bias + residual, LN2 stats
#pragma unroll
  for (int i = 0; i < 4; ++i)
#pragma unroll
    for (int r = 0; r < 4; ++r) {
      int row = i * 16 + q * 4 + r;
      float a0 = 0.f, b0 = 0.f;
#pragma unroll
      for (int j = 0; j < 4; ++j) {
        int col = w * 64 + j * 16 + m;
        float v = acc[i][j][r] + bos[col] + bf2f(ar[row * 264 + col]);
        acc[i][j][r] = v; a0 += v; b0 += v * v;
      }
      s1v[i][r] = a0; s2v[i][r] = b0;
    }
#pragma unroll
  for (int i = 0; i < 4; ++i)
#pragma unroll
    for (int r = 0; r < 4; ++r)
#pragma unroll
      for (int msk = 1; msk < 16; msk <<= 1) {
        s1v[i][r] += __shfl_xor(s1v[i][r], msk, 64);
        s2v[i][r] += __shfl_xor(s2v[i][r], msk, 64);
      }
  if (m == 0) {
#pragma unroll
    for (int i = 0; i < 4; ++i)
#pragma unroll
      for (int r = 0; r < 4; ++r) {
        ws1[i * 16 + q * 4 + r][w] = s1v[i][r];
        ws2[i * 16 + q * 4 + r][w] = s2v[i][r];
      }
  }
  __syncthreads();
  if (t < 64) {
    float a0 = 0.f, b0 = 0.f;
#pragma unroll
    for (int ww = 0; ww < 4; ++ww) { a0 += ws1[t][ww]; b0 += ws2[t][ww]; }
    float mean = a0 * (1.f / 256.f);
    float var = b0 * (1.f / 256.f) - mean * mean;
    msh[t] = mean; rsh[t] = rsqrtf(var + 1e-5f);
  }
  __syncthreads();

#pragma unroll
  for (int i = 0; i < 4; ++i)
#pragma unroll
    for (int r = 0; r < 4; ++r) {
      int row = i * 16 + q * 4 + r;
      float mean = msh[row], rst = rsh[row];
#pragma unroll
      for (int j = 0; j < 4; ++j) {
        int col = w * 64 + j * 16 + m;
        float v = (acc[i][j][r] - mean) * rst * g2s[col] + b2s[col];
        out[(row0 + row) * 256 + col] = fmaxf(v, 0.f);
      }
    }
}

extern "C" void kernel_launch(void* const* d_in, const int* in_sizes, int n_in,
                              void* d_out, int out_size, void* d_ws, size_t ws_size,
                              hipStream_t stream) {
  const float* x    = (const float*)d_in[0];
  const float* Wq   = (const float*)d_in[1];
  const float* Wk   = (const float*)d_in[2];
  const float* Wv   = (const float*)d_in[3];
  const float* Wo   = (const float*)d_in[4];
  const float* pos  = (const float*)d_in[5];
  const float* Wout = (const float*)d_in[6];
  const float* bo   = (const float*)d_in[7];
  const float* g1   = (const float*)d_in[8];
  const float* b1   = (const float*)d_in[9];
  const float* g2   = (const float*)d_in[10];
  const float* b2   = (const float*)d_in[11];
  float* out = (float*)d_out;

  const size_t nel = (size_t)NB * LL * DD;
  char* wsb = (char*)d_ws;
  short* XB   = (short*)wsb; wsb += nel * 2;
  short* XQb  = (short*)wsb; wsb += nel * 2;
  short* XKb  = (short*)wsb; wsb += nel * 2;
  short* XVb  = (short*)wsb; wsb += nel * 2;
  short* CTXB = (short*)wsb; wsb += nel * 2;
  short* WqT   = (short*)wsb; wsb += 65536 * 2;
  short* WkT   = (short*)wsb; wsb += 65536 * 2;
  short* WvT   = (short*)wsb; wsb += 65536 * 2;
  short* WoT   = (short*)wsb; wsb += 65536 * 2;
  short* WoutB = (short*)wsb; wsb += 65536 * 2;
  short* PQb = (short*)wsb; wsb += WNN * DD * 2;
  short* PKb = (short*)wsb; wsb += WNN * DD * 2;
  short* PVb = (short*)wsb; wsb += WNN * DD * 2;

  prep_all<<<(unsigned)(32 + nel / 4 / 256), 256, 0, stream>>>(
      x, XB, Wq, Wk, Wv, Wo, Wout, WqT, WkT, WvT, WoT, WoutB, pos, PQb, PKb, PVb);
  qkv_mfma<<<dim3((unsigned)(NB * LL / 64), 3), 256, 0, stream>>>(XB, WqT, WkT, WvT, XQb, XKb, XVb);
  attn_kernel<<<NB * (LL / CW), 256, 0, stream>>>(XQb, XKb, XVb, PQb, PKb, PVb, CTXB);
  out_mfma<<<(unsigned)(NB * LL / 64), 256, 0, stream>>>(CTXB, x, WoT, WoutB, bo, g1, b1, g2, b2, out);
}